// Round 3
// baseline (284.775 us; speedup 1.0000x reference)
//
#include <hip/hip_runtime.h>
#include <stdint.h>

#define HIDDEN 1024
#define HEADS 16
#define HEAD_DIM 64
#define BATCH 4
#define SEQ 2048
#define ROWS (BATCH * SEQ) /* 8192 */

typedef float f32x4 __attribute__((ext_vector_type(4)));
typedef short bf16x8 __attribute__((ext_vector_type(8))); // 8 bf16 = 4 VGPRs

__device__ __forceinline__ uint16_t f32_to_bf16_rne(float f) {
    uint32_t u = __float_as_uint(f);
    uint32_t r = u + 0x7FFFu + ((u >> 16) & 1u);
    return (uint16_t)(r >> 16);
}
__device__ __forceinline__ float bf16_to_f32(uint16_t u) {
    return __uint_as_float(((uint32_t)u) << 16);
}

// ---------------------------------------------------------------------------
// Kernel 0: convert X (q,k,v inputs) fp32 -> bf16, streaming.
// ---------------------------------------------------------------------------
__global__ __launch_bounds__(256) void cvt_kernel(const float* __restrict__ Xq,
                                                  const float* __restrict__ Xk,
                                                  const float* __restrict__ Xv,
                                                  uint16_t* __restrict__ Xb) {
    int z = blockIdx.x >> 12;
    const float* X = z == 0 ? Xq : (z == 1 ? Xk : Xv);
    uint16_t* out = Xb + (size_t)z * ROWS * HIDDEN;
    size_t e = ((size_t)(blockIdx.x & 4095) * 256 + threadIdx.x) * 8;
    float4 f0 = *(const float4*)(X + e);
    float4 f1 = *(const float4*)(X + e + 4);
    uint4 pk;
    pk.x = (uint32_t)f32_to_bf16_rne(f0.x) | ((uint32_t)f32_to_bf16_rne(f0.y) << 16);
    pk.y = (uint32_t)f32_to_bf16_rne(f0.z) | ((uint32_t)f32_to_bf16_rne(f0.w) << 16);
    pk.z = (uint32_t)f32_to_bf16_rne(f1.x) | ((uint32_t)f32_to_bf16_rne(f1.y) << 16);
    pk.w = (uint32_t)f32_to_bf16_rne(f1.z) | ((uint32_t)f32_to_bf16_rne(f1.w) << 16);
    *(uint4*)(out + e) = pk;
}

// ---------------------------------------------------------------------------
// Kernel 1: W[K][N] fp32 -> Wt[N][K] bf16, z in {Wk, Wv} only (Wq stays fp32)
// ---------------------------------------------------------------------------
__global__ __launch_bounds__(256) void wt_kernel(const float* __restrict__ Wk,
                                                 const float* __restrict__ Wv,
                                                 uint16_t* __restrict__ Wt) {
    const float* W = blockIdx.z == 0 ? Wk : Wv;
    uint16_t* out = Wt + (size_t)blockIdx.z * HIDDEN * HIDDEN;
    __shared__ float tile[64][65];
    int k0 = blockIdx.x * 64, n0 = blockIdx.y * 64;
    int r = threadIdx.x >> 6, c = threadIdx.x & 63;
    for (int it = 0; it < 16; ++it) {
        int rr = r + 4 * it;
        tile[rr][c] = W[(size_t)(k0 + rr) * HIDDEN + n0 + c];
    }
    __syncthreads();
    for (int it = 0; it < 16; ++it) {
        int rr = r + 4 * it;
        out[(size_t)(n0 + rr) * HIDDEN + k0 + c] = f32_to_bf16_rne(tile[c][rr]);
    }
}

// ---------------------------------------------------------------------------
// Kernel 2a: K projection GEMM (z=0 only), 256x256 8-phase, REGISTER-DIETED.
//   Budget analysis: 512-thr block = 2 waves/SIMD hard -> 256 unified regs/wave.
//   acc = 128 (AGPR half). Arch half must hold frags(64) + addressing + misc.
//   Diet: STAGE lane-offsets hoisted to 2 VGPRs (saddr-form loads); all ds_read
//   addresses reduced to 2 per-lane base pointers + uniform immediates.
//   Schedule is bit-identical to the round-1/2 verified pipeline.
// ---------------------------------------------------------------------------

#define STAGE(GSRC, CHUNKBASE)                                                   \
    {                                                                            \
        __builtin_amdgcn_global_load_lds(                                        \
            (const __attribute__((address_space(1))) uint32_t*)((GSRC) + soff0), \
            (__attribute__((address_space(3))) uint32_t*)(lds + (CHUNKBASE) * 8 + ldst0), \
            16, 0, 0);                                                           \
        __builtin_amdgcn_global_load_lds(                                        \
            (const __attribute__((address_space(1))) uint32_t*)((GSRC) + soff1), \
            (__attribute__((address_space(3))) uint32_t*)(lds + (CHUNKBASE) * 8 + ldst1), \
            16, 0, 0);                                                           \
    }

// A quadrant (4 M-frags x 2 k-slices). BUF/MH compile-time; wm folded via pkA*.
#define LDA(BUF, MH, AQ)                                                         \
    {                                                                            \
        _Pragma("unroll") for (int i = 0; i < 4; ++i) {                          \
            AQ[i][0] = *(const bf16x8*)(pkA0 + (BUF) + ((MH)*64 + i*16) * 64);   \
            AQ[i][1] = *(const bf16x8*)(pkA1 + (BUF) + ((MH)*64 + i*16) * 64);   \
        }                                                                        \
    }

// B quadrant (2 N-frags x 2 k-slices).
#define LDB(BUF, NH, BQ)                                                         \
    {                                                                            \
        _Pragma("unroll") for (int j = 0; j < 2; ++j) {                          \
            BQ[j][0] = *(const bf16x8*)(pkB0 + (BUF) + ((NH)*32 + j*16) * 64);   \
            BQ[j][1] = *(const bf16x8*)(pkB1 + (BUF) + ((NH)*32 + j*16) * 64);   \
        }                                                                        \
    }

#define MFMA_QUAD(AQ, BQ, MH, NH)                                                \
    {                                                                            \
        _Pragma("unroll") for (int ks = 0; ks < 2; ++ks)                         \
        _Pragma("unroll") for (int i = 0; i < 4; ++i)                            \
        _Pragma("unroll") for (int j = 0; j < 2; ++j)                            \
            acc[(MH) * 4 + i][(NH) * 2 + j] =                                    \
                __builtin_amdgcn_mfma_f32_16x16x32_bf16(                         \
                    AQ[i][ks], BQ[j][ks], acc[(MH) * 4 + i][(NH) * 2 + j], 0, 0, 0); \
    }

#define PHASE_MID()                                                              \
    __builtin_amdgcn_s_barrier();                                                \
    asm volatile("s_waitcnt lgkmcnt(0)" ::: "memory");                           \
    __builtin_amdgcn_s_setprio(1);

#define PHASE_END()                                                              \
    __builtin_amdgcn_s_setprio(0);                                               \
    __builtin_amdgcn_s_barrier();

__global__ __launch_bounds__(512, 1) void proj_gemm8(const uint16_t* __restrict__ X,
                                                     const uint16_t* __restrict__ W,
                                                     const float* __restrict__ bias,
                                                     uint16_t* __restrict__ out) {
    extern __shared__ uint16_t lds[]; // 131072 B: buf0 A|B, buf1 A|B (32KB each)

    const int tid = threadIdx.x;
    const int lane = tid & 63;
    const int w = tid >> 6;          // 8 waves
    const int wm = (w >> 2) * 128;   // warp_m in {0,128}
    const int wn = (w & 3) * 64;     // warp_n in {0,64,128,192}
    const int m_lane = lane & 15;
    const int kq = lane >> 4;
    const int m0 = blockIdx.x * 256;
    const int n0 = blockIdx.y * 256;

    const uint16_t* Xb = X + (size_t)m0 * HIDDEN; // A rows base
    const uint16_t* Wb = W + (size_t)n0 * HIDDEN; // B rows base

    // --- hoisted per-lane STAGE offsets (2 VGPRs) + wave-uniform LDS dests ---
    const int gA = w * 64 + lane;
    const int rA = gA >> 3, cA = (gA & 7) ^ (rA & 7);
    const int soff0 = rA * HIDDEN + cA * 8;
    const int gB = 512 + w * 64 + lane;
    const int rB = gB >> 3, cB = (gB & 7) ^ (rB & 7);
    const int soff1 = rB * HIDDEN + cB * 8;
    const int ldst0 = (w * 64) * 8;
    const int ldst1 = (512 + w * 64) * 8;

    // --- hoisted per-lane ds_read base pointers ---
    // elem = BUF + [16384] + (row_base + m_lane)*64 + ((ks*4+kq)^(m_lane&7))*8
    const int pswz0 = (kq ^ (m_lane & 7)) * 8;
    const int pswz1 = ((4 ^ kq) ^ (m_lane & 7)) * 8;
    const uint16_t* pkA0 = lds + wm * 64 + m_lane * 64 + pswz0;
    const uint16_t* pkA1 = lds + wm * 64 + m_lane * 64 + pswz1;
    const uint16_t* pkB0 = lds + 16384 + wn * 64 + m_lane * 64 + pswz0;
    const uint16_t* pkB1 = lds + 16384 + wn * 64 + m_lane * 64 + pswz1;

    f32x4 acc[8][4] = {};
    bf16x8 aq[4][2], b0q[2][2], b1q[2][2];

    // ---- prologue: T0 fully (A0,A1,B0,B1) + T1.B0,B1; wait T0 landed ----
    STAGE(Xb, 0);                              // T0.A0 -> buf0 chunks [0,1024)
    STAGE(Xb + 128 * HIDDEN, 1024);            // T0.A1
    STAGE(Wb, 2048);                           // T0.B0
    STAGE(Wb + 128 * HIDDEN, 3072);            // T0.B1
    STAGE(Wb + 64, 4096 + 2048);               // T1.B0 -> buf1.B
    STAGE(Wb + 128 * HIDDEN + 64, 4096 + 3072);// T1.B1
    asm volatile("s_waitcnt vmcnt(4)" ::: "memory"); // T0 landed (newest 4 = T1.B)
    __builtin_amdgcn_s_barrier();

    // ---- main: 7 iters, 2 K-tiles each; tiles 0..13 consumed, stage thru 15.B
#pragma unroll 1
    for (int i = 0; i < 7; ++i) {
        const int kb = i * 128;
        // ph1: quad(0,0) of tile 2i [buf0]; stage T(2i+1).A0 -> buf1
        LDA(0, 0, aq); LDB(0, 0, b0q);
        STAGE(Xb + kb + 64, 4096 + 0);
        PHASE_MID(); MFMA_QUAD(aq, b0q, 0, 0); PHASE_END();
        // ph2: quad(0,1); stage T(2i+1).A1
        LDB(0, 1, b1q);
        STAGE(Xb + 128 * HIDDEN + kb + 64, 4096 + 1024);
        PHASE_MID(); MFMA_QUAD(aq, b1q, 0, 1); PHASE_END();
        // ph3: quad(1,1); stage T(2i+2).B0 -> buf0.B (freed after ph2)
        LDA(0, 1, aq);
        STAGE(Wb + kb + 128, 2048);
        PHASE_MID(); MFMA_QUAD(aq, b1q, 1, 1); PHASE_END();
        // ph4: quad(1,0); stage T(2i+2).B1; counted vmcnt: tile 2i+1 landed
        STAGE(Wb + 128 * HIDDEN + kb + 128, 3072);
        asm volatile("s_waitcnt vmcnt(4)" ::: "memory");
        __builtin_amdgcn_s_barrier();
        __builtin_amdgcn_s_setprio(1);
        MFMA_QUAD(aq, b0q, 1, 0);
        PHASE_END();
        // ph5: quad(0,0) of tile 2i+1 [buf1]; stage T(2i+2).A0 -> buf0.A
        LDA(32768, 0, aq); LDB(32768, 0, b0q);
        STAGE(Xb + kb + 128, 0);
        PHASE_MID(); MFMA_QUAD(aq, b0q, 0, 0); PHASE_END();
        // ph6: quad(0,1); stage T(2i+2).A1
        LDB(32768, 1, b1q);
        STAGE(Xb + 128 * HIDDEN + kb + 128, 1024);
        PHASE_MID(); MFMA_QUAD(aq, b1q, 0, 1); PHASE_END();
        // ph7: quad(1,1); stage T(2i+3).B0 -> buf1.B (freed after ph6)
        LDA(32768, 1, aq);
        STAGE(Wb + kb + 192, 4096 + 2048);
        PHASE_MID(); MFMA_QUAD(aq, b1q, 1, 1); PHASE_END();
        // ph8: quad(1,0); stage T(2i+3).B1; counted vmcnt: tile 2i+2 landed
        STAGE(Wb + 128 * HIDDEN + kb + 192, 4096 + 3072);
        asm volatile("s_waitcnt vmcnt(4)" ::: "memory");
        __builtin_amdgcn_s_barrier();
        __builtin_amdgcn_s_setprio(1);
        MFMA_QUAD(aq, b0q, 1, 0);
        PHASE_END();
    }

    // ---- epilogue iteration: tiles 14 [buf0], 15 [buf1]; stage only T15.A ----
    {
        const int kb = 896;
        LDA(0, 0, aq); LDB(0, 0, b0q);
        STAGE(Xb + kb + 64, 4096 + 0);             // T15.A0
        PHASE_MID(); MFMA_QUAD(aq, b0q, 0, 0); PHASE_END();
        LDB(0, 1, b1q);
        STAGE(Xb + 128 * HIDDEN + kb + 64, 4096 + 1024); // T15.A1
        PHASE_MID(); MFMA_QUAD(aq, b1q, 0, 1); PHASE_END();
        LDA(0, 1, aq);
        PHASE_MID(); MFMA_QUAD(aq, b1q, 1, 1); PHASE_END();
        asm volatile("s_waitcnt vmcnt(0)" ::: "memory"); // T15 fully landed
        __builtin_amdgcn_s_barrier();
        __builtin_amdgcn_s_setprio(1);
        MFMA_QUAD(aq, b0q, 1, 0);
        PHASE_END();
        LDA(32768, 0, aq); LDB(32768, 0, b0q);
        PHASE_MID(); MFMA_QUAD(aq, b0q, 0, 0); PHASE_END();
        LDB(32768, 1, b1q);
        PHASE_MID(); MFMA_QUAD(aq, b1q, 0, 1); PHASE_END();
        LDA(32768, 1, aq);
        PHASE_MID(); MFMA_QUAD(aq, b1q, 1, 1); PHASE_END();
        __builtin_amdgcn_s_setprio(1);
        MFMA_QUAD(aq, b0q, 1, 0);
        __builtin_amdgcn_s_setprio(0);
    }

    // ---- C write: per wave 128x64, same C/D mapping as verified kernel ----
    for (int nj = 0; nj < 4; ++nj) {
        int col = n0 + wn + nj * 16 + m_lane;
        float bj = bias[col];
        for (int mi = 0; mi < 8; ++mi) {
            int rbase = m0 + wm + mi * 16 + kq * 4;
            for (int rg = 0; rg < 4; ++rg) {
                float v = acc[mi][nj][rg] + bj;
                out[(size_t)(rbase + rg) * HIDDEN + col] = f32_to_bf16_rne(v);
            }
        }
    }
}

// ---------------------------------------------------------------------------
// Kernel 2b: V projection GEMM — round-0 verified m97 128x128 structure.
//   Launched with gridDim.z=1 and V-offset pointers (z=0 path selects them).
// ---------------------------------------------------------------------------
__global__ __launch_bounds__(256) void proj_gemm(const uint16_t* __restrict__ Xkv,
                                                 const uint16_t* __restrict__ Wt,
                                                 const float* __restrict__ Bk,
                                                 const float* __restrict__ Bv,
                                                 uint16_t* __restrict__ KV) {
    const int z = blockIdx.z;
    const uint16_t* X = Xkv + (size_t)z * ROWS * HIDDEN;
    const uint16_t* W = Wt + (size_t)z * HIDDEN * HIDDEN;
    const float* bias = z == 0 ? Bk : Bv;
    uint16_t* out = KV + (size_t)z * ROWS * HIDDEN;

    __shared__ uint16_t slds[16384]; // A: [0,8192), B: [8192,16384)

    const int tid = threadIdx.x;
    const int lane = tid & 63;
    const int w = tid >> 6;
    const int wm = (w >> 1) * 64;
    const int wn = (w & 1) * 64;
    const int m_lane = lane & 15;
    const int kq = lane >> 4;
    const int m0 = blockIdx.x * 128;
    const int n0 = blockIdx.y * 128;

    f32x4 acc[4][4] = {};

    for (int kb = 0; kb < HIDDEN; kb += 64) {
        for (int t = 0; t < 4; ++t) {
            int gbase = (w * 4 + t) * 64;
            int g = gbase + lane;
            int r = g >> 3;
            int c = (g & 7) ^ (r & 7);
            const uint16_t* srcA = X + (size_t)(m0 + r) * HIDDEN + kb + c * 8;
            __builtin_amdgcn_global_load_lds(
                (const __attribute__((address_space(1))) uint32_t*)srcA,
                (__attribute__((address_space(3))) uint32_t*)(&slds[gbase * 8]),
                16, 0, 0);
            const uint16_t* srcB = W + (size_t)(n0 + r) * HIDDEN + kb + c * 8;
            __builtin_amdgcn_global_load_lds(
                (const __attribute__((address_space(1))) uint32_t*)srcB,
                (__attribute__((address_space(3))) uint32_t*)(&slds[8192 + gbase * 8]),
                16, 0, 0);
        }
        __syncthreads();
        for (int ks = 0; ks < 2; ++ks) {
            int cbase = ks * 4 + kq;
            bf16x8 af[4], bfr[4];
            for (int i = 0; i < 4; ++i) {
                int r = wm + i * 16 + m_lane;
                int p = cbase ^ (r & 7);
                af[i] = *(const bf16x8*)(&slds[r * 64 + p * 8]);
            }
            for (int j = 0; j < 4; ++j) {
                int nr = wn + j * 16 + m_lane;
                int p = cbase ^ (nr & 7);
                bfr[j] = *(const bf16x8*)(&slds[8192 + nr * 64 + p * 8]);
            }
            for (int i = 0; i < 4; ++i)
                for (int j = 0; j < 4; ++j)
                    acc[i][j] = __builtin_amdgcn_mfma_f32_16x16x32_bf16(
                        af[i], bfr[j], acc[i][j], 0, 0, 0);
        }
        __syncthreads();
    }

    for (int j = 0; j < 4; ++j) {
        int col = n0 + wn + j * 16 + m_lane;
        float bj = bias[col];
        for (int i = 0; i < 4; ++i) {
            int rbase = m0 + wm + i * 16 + kq * 4;
            for (int rg = 0; rg < 4; ++rg) {
                float v = acc[i][j][rg] + bj;
                out[(size_t)(rbase + rg) * HIDDEN + col] = f32_to_bf16_rne(v);
            }
        }
    }
}

// ---------------------------------------------------------------------------
// Kernel 3: P[bh][sc] = (1/8) * K_h^T V_h over a 256-row S chunk.
//   NO atomics: each block owns a private 64x64 fp32 partial.
// ---------------------------------------------------------------------------
__global__ __launch_bounds__(256) void kv_kernel(const uint16_t* __restrict__ KV,
                                                 float* __restrict__ P) {
    const uint16_t* K = KV;
    const uint16_t* V = KV + (size_t)ROWS * HIDDEN;
    const int bh = blockIdx.x;  // b*16+h
    const int sc = blockIdx.y;  // 0..7, 256 rows each
    const int b = bh >> 4, h = bh & 15;
    const int tid = threadIdx.x;
    const size_t base = ((size_t)b * SEQ + sc * 256) * HIDDEN + h * 64;

    __shared__ float kk[16][64];
    __shared__ float vv[16][64];
    float acc[4][4] = {};
    const int i0 = (tid >> 4) * 4, j0 = (tid & 15) * 4;

    for (int batch = 0; batch < 16; ++batch) {
        __syncthreads();
        {
            int t = tid & 127;
            int row = t >> 3, c = t & 7;
            const uint16_t* src =
                (tid < 128 ? K : V) + base + (size_t)(batch * 16 + row) * HIDDEN + c * 8;
            float* dst = (tid < 128 ? &kk[row][c * 8] : &vv[row][c * 8]);
            bf16x8 d = *(const bf16x8*)src;
            for (int e = 0; e < 8; ++e) dst[e] = bf16_to_f32((uint16_t)d[e]);
        }
        __syncthreads();
        for (int r = 0; r < 16; ++r) {
            f32x4 ka = *(const f32x4*)(&kk[r][i0]);
            f32x4 va = *(const f32x4*)(&vv[r][j0]);
            for (int a = 0; a < 4; ++a)
                for (int bb = 0; bb < 4; ++bb)
                    acc[a][bb] += ka[a] * va[bb];
        }
    }
    float* Pp = P + ((size_t)bh * 8 + sc) * 4096;
    for (int a = 0; a < 4; ++a) {
        f32x4 row;
        for (int bb = 0; bb < 4; ++bb) row[bb] = acc[a][bb] * 0.125f;
        *(f32x4*)(&Pp[(i0 + a) * 64 + j0]) = row;
    }
}

// ---------------------------------------------------------------------------
// Kernel 4: fold M into weights — PER BATCH. Sums the 8 kv partials inline.
// ---------------------------------------------------------------------------
__global__ __launch_bounds__(256) void wprime_kernel(const float* __restrict__ Wq,
                                                     const float* __restrict__ bq,
                                                     const float* __restrict__ P,
                                                     uint16_t* __restrict__ Wpt,
                                                     float* __restrict__ bp) {
    const int h = blockIdx.x;
    const int r0 = blockIdx.y * 64;
    const int b = blockIdx.z;
    const int tid = threadIdx.x;

    __shared__ float Mh[64][65];
    __shared__ float Wl[64][65];
    const float* Pp = P + ((size_t)(b * 16 + h)) * 8 * 4096;
    for (int it = 0; it < 16; ++it) {
        int e = it * 256 + tid;
        int a = e >> 6, c = e & 63;
        float s = 0.f;
        for (int sc = 0; sc < 8; ++sc) s += Pp[sc * 4096 + e];
        Mh[a][c] = s;
        Wl[a][c] = Wq[(size_t)(r0 + a) * HIDDEN + h * 64 + c];
    }
    __syncthreads();

    const int r = tid & 63;
    const int jbase = tid >> 6; // 0..3
    float acc[16] = {};
    for (int i = 0; i < 64; ++i) {
        float wv = Wl[r][i];
        for (int jj = 0; jj < 16; ++jj)
            acc[jj] += wv * Mh[i][jbase + 4 * jj];
    }
    uint16_t* Wb = Wpt + (size_t)b * HIDDEN * HIDDEN;
    for (int jj = 0; jj < 16; ++jj) {
        int n = h * 64 + jbase + 4 * jj;
        Wb[(size_t)n * HIDDEN + r0 + r] = f32_to_bf16_rne(acc[jj]);
    }

    if (blockIdx.y == 0 && tid < 64) {
        int j = tid;
        float s = 0.f;
        for (int i = 0; i < 64; ++i) s += bq[h * 64 + i] * Mh[i][j];
        bp[b * HIDDEN + h * 64 + j] = s;
    }
}

// ---------------------------------------------------------------------------
// Kernel 5: out = Xq @ W'_b^T + b'_b   (fp32 output to d_out)
// ---------------------------------------------------------------------------
__global__ __launch_bounds__(256) void final_gemm(const uint16_t* __restrict__ Xq,
                                                  const uint16_t* __restrict__ Wpt,
                                                  const float* __restrict__ bp,
                                                  float* __restrict__ out) {
    __shared__ uint16_t slds[16384];

    const int tid = threadIdx.x;
    const int lane = tid & 63;
    const int w = tid >> 6;
    const int wm = (w >> 1) * 64;
    const int wn = (w & 1) * 64;
    const int m_lane = lane & 15;
    const int kq = lane >> 4;
    const int m0 = blockIdx.x * 128;
    const int n0 = blockIdx.y * 128;
    const int batch = m0 >> 11;
    const uint16_t* W = Wpt + (size_t)batch * HIDDEN * HIDDEN;
    const float* bias = bp + batch * HIDDEN;

    f32x4 acc[4][4] = {};

    for (int kb = 0; kb < HIDDEN; kb += 64) {
        for (int t = 0; t < 4; ++t) {
            int gbase = (w * 4 + t) * 64;
            int g = gbase + lane;
            int r = g >> 3;
            int c = (g & 7) ^ (r & 7);
            const uint16_t* srcA = Xq + (size_t)(m0 + r) * HIDDEN + kb + c * 8;
            __builtin_amdgcn_global_load_lds(
                (const __attribute__((address_space(1))) uint32_t*)srcA,
                (__attribute__((address_space(3))) uint32_t*)(&slds[gbase * 8]),
                16, 0, 0);
            const uint16_t* srcB = W + (size_t)(n0 + r) * HIDDEN + kb + c * 8;
            __builtin_amdgcn_global_load_lds(
                (const __attribute__((address_space(1))) uint32_t*)srcB,
                (__attribute__((address_space(3))) uint32_t*)(&slds[8192 + gbase * 8]),
                16, 0, 0);
        }
        __syncthreads();
        for (int ks = 0; ks < 2; ++ks) {
            int cbase = ks * 4 + kq;
            bf16x8 af[4], bfr[4];
            for (int i = 0; i < 4; ++i) {
                int r = wm + i * 16 + m_lane;
                int p = cbase ^ (r & 7);
                af[i] = *(const bf16x8*)(&slds[r * 64 + p * 8]);
            }
            for (int j = 0; j < 4; ++j) {
                int nr = wn + j * 16 + m_lane;
                int p = cbase ^ (nr & 7);
                bfr[j] = *(const bf16x8*)(&slds[8192 + nr * 64 + p * 8]);
            }
            for (int i = 0; i < 4; ++i)
                for (int j = 0; j < 4; ++j)
                    acc[i][j] = __builtin_amdgcn_mfma_f32_16x16x32_bf16(
                        af[i], bfr[j], acc[i][j], 0, 0, 0);
        }
        __syncthreads();
    }

    for (int j = 0; j < 4; ++j) {
        int col = n0 + wn + j * 16 + m_lane;
        float bj = bias[col];
        for (int i = 0; i < 4; ++i) {
            int rbase = m0 + wm + i * 16 + kq * 4;
            for (int rg = 0; rg < 4; ++rg)
                out[(size_t)(rbase + rg) * HIDDEN + col] = acc[i][j][rg] + bj;
        }
    }
}

// ---------------------------------------------------------------------------
extern "C" void kernel_launch(void* const* d_in, const int* in_sizes, int n_in,
                              void* d_out, int out_size, void* d_ws, size_t ws_size,
                              hipStream_t stream) {
    const float* Xq = (const float*)d_in[0];
    const float* Xk = (const float*)d_in[1];
    const float* Xv = (const float*)d_in[2];
    const float* Wq = (const float*)d_in[3];
    const float* Bq = (const float*)d_in[4];
    const float* Wk = (const float*)d_in[5];
    const float* Bk = (const float*)d_in[6];
    const float* Wv = (const float*)d_in[7];
    const float* Bv = (const float*)d_in[8];
    float* out = (float*)d_out;

    char* ws = (char*)d_ws;
    uint16_t* Xb = (uint16_t*)ws;                        // 50,331,648 B (Xq,Xk,Xv bf16)
    uint16_t* KV = (uint16_t*)(ws + 50331648);           // 33,554,432 B (K,V bf16)
    uint16_t* Wt = (uint16_t*)(ws + 83886080);           //  4,194,304 B (Wk,Wv bf16 T)
    float* P = (float*)(ws + 88080384);                  //  8,388,608 B (64bh x 8sc x 4096)
    uint16_t* Wpt = (uint16_t*)(ws + 96468992);          //  8,388,608 B (4 x W'_b)
    float* bp = (float*)(ws + 104857600);                //     16,384 B (~100 MB)

    static bool attr_done = false;
    if (!attr_done) {
        (void)hipFuncSetAttribute((const void*)proj_gemm8,
                                  hipFuncAttributeMaxDynamicSharedMemorySize, 131072);
        attr_done = true;
    }

    cvt_kernel<<<dim3(3 * 4096), 256, 0, stream>>>(Xq, Xk, Xv, Xb);
    wt_kernel<<<dim3(16, 16, 2), 256, 0, stream>>>(Wk, Wv, Wt);

    const uint16_t* Xkv = Xb + (size_t)ROWS * HIDDEN;
    // z=0 (K): dieted 8-phase 256^2 kernel.
    proj_gemm8<<<dim3(32, 4), 512, 131072, stream>>>(Xkv, Wt, Bk, KV);
    // z=1 (V): round-0-verified m97 128^2 kernel, via offset pointers (A/B ref).
    proj_gemm<<<dim3(64, 8, 1), 256, 0, stream>>>(
        Xkv + (size_t)ROWS * HIDDEN, Wt + (size_t)HIDDEN * HIDDEN, Bv, Bv,
        KV + (size_t)ROWS * HIDDEN);

    kv_kernel<<<dim3(64, 8), 256, 0, stream>>>(KV, P);
    wprime_kernel<<<dim3(16, 16, 4), 256, 0, stream>>>(Wq, Bq, P, Wpt, bp);
    final_gemm<<<dim3(64, 8), 256, 0, stream>>>(Xb, Wpt, bp, out);
}

// Round 4
// 269.556 us; speedup vs baseline: 1.0565x; 1.0565x over previous
//
#include <hip/hip_runtime.h>
#include <stdint.h>

#define HIDDEN 1024
#define HEADS 16
#define HEAD_DIM 64
#define BATCH 4
#define SEQ 2048
#define ROWS (BATCH * SEQ) /* 8192 */

typedef float f32x4 __attribute__((ext_vector_type(4)));
typedef short bf16x8 __attribute__((ext_vector_type(8))); // 8 bf16 = 4 VGPRs

__device__ __forceinline__ uint16_t f32_to_bf16_rne(float f) {
    uint32_t u = __float_as_uint(f);
    uint32_t r = u + 0x7FFFu + ((u >> 16) & 1u);
    return (uint16_t)(r >> 16);
}
__device__ __forceinline__ float bf16_to_f32(uint16_t u) {
    return __uint_as_float(((uint32_t)u) << 16);
}

// ---------------------------------------------------------------------------
// Kernel 0: convert X (q,k,v inputs) fp32 -> bf16, streaming.
//   Fully-coalesced variant: 1 float4 load (16B/lane contiguous) + 1 uint2
//   store (8B/lane contiguous) per thread. Round-3's stride-32B per-lane
//   pattern spanned 2048B per load instruction (2x cacheline requests) and
//   held the kernel at 3.5 TB/s.
// ---------------------------------------------------------------------------
__global__ __launch_bounds__(256) void cvt_kernel(const float* __restrict__ Xq,
                                                  const float* __restrict__ Xk,
                                                  const float* __restrict__ Xv,
                                                  uint16_t* __restrict__ Xb) {
    int z = blockIdx.x >> 13; // 8192 blocks per array
    const float* X = z == 0 ? Xq : (z == 1 ? Xk : Xv);
    uint16_t* out = Xb + (size_t)z * ROWS * HIDDEN;
    size_t i4 = (size_t)(blockIdx.x & 8191) * 256 + threadIdx.x; // float4 index
    float4 f = ((const float4*)X)[i4];
    uint2 pk;
    pk.x = (uint32_t)f32_to_bf16_rne(f.x) | ((uint32_t)f32_to_bf16_rne(f.y) << 16);
    pk.y = (uint32_t)f32_to_bf16_rne(f.z) | ((uint32_t)f32_to_bf16_rne(f.w) << 16);
    ((uint2*)out)[i4] = pk;
}

// ---------------------------------------------------------------------------
// Kernel 1: W[K][N] fp32 -> Wt[N][K] bf16, z in {Wk, Wv} only (Wq stays fp32)
// ---------------------------------------------------------------------------
__global__ __launch_bounds__(256) void wt_kernel(const float* __restrict__ Wk,
                                                 const float* __restrict__ Wv,
                                                 uint16_t* __restrict__ Wt) {
    const float* W = blockIdx.z == 0 ? Wk : Wv;
    uint16_t* out = Wt + (size_t)blockIdx.z * HIDDEN * HIDDEN;
    __shared__ float tile[64][65];
    int k0 = blockIdx.x * 64, n0 = blockIdx.y * 64;
    int r = threadIdx.x >> 6, c = threadIdx.x & 63;
    for (int it = 0; it < 16; ++it) {
        int rr = r + 4 * it;
        tile[rr][c] = W[(size_t)(k0 + rr) * HIDDEN + n0 + c];
    }
    __syncthreads();
    for (int it = 0; it < 16; ++it) {
        int rr = r + 4 * it;
        out[(size_t)(n0 + rr) * HIDDEN + k0 + c] = f32_to_bf16_rne(tile[c][rr]);
    }
}

// ---------------------------------------------------------------------------
// Kernel 2: K/V projection GEMM  KV[z] = Xkv[z] @ Wt[z]^T + bias  (bf16 MFMA)
//   Round-0 verified m97 structure, 128x128 tile, both z in one launch.
//   (8-phase 512-thread variants abandoned: 2 waves/SIMD caps the unified
//   RF at 256 regs/wave; acc alone is 128 -> unavoidable spills, 3 rounds.)
// ---------------------------------------------------------------------------
__global__ __launch_bounds__(256) void proj_gemm(const uint16_t* __restrict__ Xkv,
                                                 const uint16_t* __restrict__ Wt,
                                                 const float* __restrict__ Bk,
                                                 const float* __restrict__ Bv,
                                                 uint16_t* __restrict__ KV) {
    const int z = blockIdx.z; // 0=K, 1=V
    const uint16_t* X = Xkv + (size_t)z * ROWS * HIDDEN;
    const uint16_t* W = Wt + (size_t)z * HIDDEN * HIDDEN;
    const float* bias = z == 0 ? Bk : Bv;
    uint16_t* out = KV + (size_t)z * ROWS * HIDDEN;

    __shared__ uint16_t slds[16384]; // A: [0,8192), B: [8192,16384)

    const int tid = threadIdx.x;
    const int lane = tid & 63;
    const int w = tid >> 6;
    const int wm = (w >> 1) * 64;
    const int wn = (w & 1) * 64;
    const int m_lane = lane & 15;
    const int kq = lane >> 4;
    const int m0 = blockIdx.x * 128;
    const int n0 = blockIdx.y * 128;

    f32x4 acc[4][4] = {};

    for (int kb = 0; kb < HIDDEN; kb += 64) {
        for (int t = 0; t < 4; ++t) {
            int gbase = (w * 4 + t) * 64;
            int g = gbase + lane;
            int r = g >> 3;
            int c = (g & 7) ^ (r & 7);
            const uint16_t* srcA = X + (size_t)(m0 + r) * HIDDEN + kb + c * 8;
            __builtin_amdgcn_global_load_lds(
                (const __attribute__((address_space(1))) uint32_t*)srcA,
                (__attribute__((address_space(3))) uint32_t*)(&slds[gbase * 8]),
                16, 0, 0);
            const uint16_t* srcB = W + (size_t)(n0 + r) * HIDDEN + kb + c * 8;
            __builtin_amdgcn_global_load_lds(
                (const __attribute__((address_space(1))) uint32_t*)srcB,
                (__attribute__((address_space(3))) uint32_t*)(&slds[8192 + gbase * 8]),
                16, 0, 0);
        }
        __syncthreads();
        for (int ks = 0; ks < 2; ++ks) {
            int cbase = ks * 4 + kq;
            bf16x8 af[4], bfr[4];
            for (int i = 0; i < 4; ++i) {
                int r = wm + i * 16 + m_lane;
                int p = cbase ^ (r & 7);
                af[i] = *(const bf16x8*)(&slds[r * 64 + p * 8]);
            }
            for (int j = 0; j < 4; ++j) {
                int nr = wn + j * 16 + m_lane;
                int p = cbase ^ (nr & 7);
                bfr[j] = *(const bf16x8*)(&slds[8192 + nr * 64 + p * 8]);
            }
            for (int i = 0; i < 4; ++i)
                for (int j = 0; j < 4; ++j)
                    acc[i][j] = __builtin_amdgcn_mfma_f32_16x16x32_bf16(
                        af[i], bfr[j], acc[i][j], 0, 0, 0);
        }
        __syncthreads();
    }

    for (int j = 0; j < 4; ++j) {
        int col = n0 + wn + j * 16 + m_lane;
        float bj = bias[col];
        for (int i = 0; i < 4; ++i) {
            int rbase = m0 + wm + i * 16 + kq * 4;
            for (int rg = 0; rg < 4; ++rg) {
                float v = acc[i][j][rg] + bj;
                out[(size_t)(rbase + rg) * HIDDEN + col] = f32_to_bf16_rne(v);
            }
        }
    }
}

// ---------------------------------------------------------------------------
// Kernel 3: P[bh][sc] = (1/8) * K_h^T V_h over a 256-row S chunk.
//   NO atomics: each block owns a private 64x64 fp32 partial.
// ---------------------------------------------------------------------------
__global__ __launch_bounds__(256) void kv_kernel(const uint16_t* __restrict__ KV,
                                                 float* __restrict__ P) {
    const uint16_t* K = KV;
    const uint16_t* V = KV + (size_t)ROWS * HIDDEN;
    const int bh = blockIdx.x;  // b*16+h
    const int sc = blockIdx.y;  // 0..7, 256 rows each
    const int b = bh >> 4, h = bh & 15;
    const int tid = threadIdx.x;
    const size_t base = ((size_t)b * SEQ + sc * 256) * HIDDEN + h * 64;

    __shared__ float kk[16][64];
    __shared__ float vv[16][64];
    float acc[4][4] = {};
    const int i0 = (tid >> 4) * 4, j0 = (tid & 15) * 4;

    for (int batch = 0; batch < 16; ++batch) {
        __syncthreads();
        {
            int t = tid & 127;
            int row = t >> 3, c = t & 7;
            const uint16_t* src =
                (tid < 128 ? K : V) + base + (size_t)(batch * 16 + row) * HIDDEN + c * 8;
            float* dst = (tid < 128 ? &kk[row][c * 8] : &vv[row][c * 8]);
            bf16x8 d = *(const bf16x8*)src;
            for (int e = 0; e < 8; ++e) dst[e] = bf16_to_f32((uint16_t)d[e]);
        }
        __syncthreads();
        for (int r = 0; r < 16; ++r) {
            f32x4 ka = *(const f32x4*)(&kk[r][i0]);
            f32x4 va = *(const f32x4*)(&vv[r][j0]);
            for (int a = 0; a < 4; ++a)
                for (int bb = 0; bb < 4; ++bb)
                    acc[a][bb] += ka[a] * va[bb];
        }
    }
    float* Pp = P + ((size_t)bh * 8 + sc) * 4096;
    for (int a = 0; a < 4; ++a) {
        f32x4 row;
        for (int bb = 0; bb < 4; ++bb) row[bb] = acc[a][bb] * 0.125f;
        *(f32x4*)(&Pp[(i0 + a) * 64 + j0]) = row;
    }
}

// ---------------------------------------------------------------------------
// Kernel 4: fold M into weights — PER BATCH. Sums the 8 kv partials inline.
//   W't[b][n=h*64+j][k=r] = sum_i Wq[r][h*64+i] * M[b*16+h][i][j]   (bf16)
//   b'[b][n]              = sum_i bq[h*64+i]    * M[b*16+h][i][j]   (fp32)
// grid (16 h, 16 rc, 4 b), block 256.
// ---------------------------------------------------------------------------
__global__ __launch_bounds__(256) void wprime_kernel(const float* __restrict__ Wq,
                                                     const float* __restrict__ bq,
                                                     const float* __restrict__ P,
                                                     uint16_t* __restrict__ Wpt,
                                                     float* __restrict__ bp) {
    const int h = blockIdx.x;
    const int r0 = blockIdx.y * 64;
    const int b = blockIdx.z;
    const int tid = threadIdx.x;

    __shared__ float Mh[64][65];
    __shared__ float Wl[64][65];
    const float* Pp = P + ((size_t)(b * 16 + h)) * 8 * 4096;
    for (int it = 0; it < 16; ++it) {
        int e = it * 256 + tid;
        int a = e >> 6, c = e & 63;
        float s = 0.f;
        for (int sc = 0; sc < 8; ++sc) s += Pp[sc * 4096 + e];
        Mh[a][c] = s;
        Wl[a][c] = Wq[(size_t)(r0 + a) * HIDDEN + h * 64 + c];
    }
    __syncthreads();

    const int r = tid & 63;
    const int jbase = tid >> 6; // 0..3
    float acc[16] = {};
    for (int i = 0; i < 64; ++i) {
        float wv = Wl[r][i];
        for (int jj = 0; jj < 16; ++jj)
            acc[jj] += wv * Mh[i][jbase + 4 * jj];
    }
    uint16_t* Wb = Wpt + (size_t)b * HIDDEN * HIDDEN;
    for (int jj = 0; jj < 16; ++jj) {
        int n = h * 64 + jbase + 4 * jj;
        Wb[(size_t)n * HIDDEN + r0 + r] = f32_to_bf16_rne(acc[jj]);
    }

    if (blockIdx.y == 0 && tid < 64) {
        int j = tid;
        float s = 0.f;
        for (int i = 0; i < 64; ++i) s += bq[h * 64 + i] * Mh[i][j];
        bp[b * HIDDEN + h * 64 + j] = s;
    }
}

// ---------------------------------------------------------------------------
// Kernel 5: out = Xq @ W'_b^T + b'_b   (fp32 output to d_out)
//   batch = m0 >> 11 (each 128-row tile lies in one batch).
// ---------------------------------------------------------------------------
__global__ __launch_bounds__(256) void final_gemm(const uint16_t* __restrict__ Xq,
                                                  const uint16_t* __restrict__ Wpt,
                                                  const float* __restrict__ bp,
                                                  float* __restrict__ out) {
    __shared__ uint16_t slds[16384];

    const int tid = threadIdx.x;
    const int lane = tid & 63;
    const int w = tid >> 6;
    const int wm = (w >> 1) * 64;
    const int wn = (w & 1) * 64;
    const int m_lane = lane & 15;
    const int kq = lane >> 4;
    const int m0 = blockIdx.x * 128;
    const int n0 = blockIdx.y * 128;
    const int batch = m0 >> 11;
    const uint16_t* W = Wpt + (size_t)batch * HIDDEN * HIDDEN;
    const float* bias = bp + batch * HIDDEN;

    f32x4 acc[4][4] = {};

    for (int kb = 0; kb < HIDDEN; kb += 64) {
        for (int t = 0; t < 4; ++t) {
            int gbase = (w * 4 + t) * 64;
            int g = gbase + lane;
            int r = g >> 3;
            int c = (g & 7) ^ (r & 7);
            const uint16_t* srcA = Xq + (size_t)(m0 + r) * HIDDEN + kb + c * 8;
            __builtin_amdgcn_global_load_lds(
                (const __attribute__((address_space(1))) uint32_t*)srcA,
                (__attribute__((address_space(3))) uint32_t*)(&slds[gbase * 8]),
                16, 0, 0);
            const uint16_t* srcB = W + (size_t)(n0 + r) * HIDDEN + kb + c * 8;
            __builtin_amdgcn_global_load_lds(
                (const __attribute__((address_space(1))) uint32_t*)srcB,
                (__attribute__((address_space(3))) uint32_t*)(&slds[8192 + gbase * 8]),
                16, 0, 0);
        }
        __syncthreads();
        for (int ks = 0; ks < 2; ++ks) {
            int cbase = ks * 4 + kq;
            bf16x8 af[4], bfr[4];
            for (int i = 0; i < 4; ++i) {
                int r = wm + i * 16 + m_lane;
                int p = cbase ^ (r & 7);
                af[i] = *(const bf16x8*)(&slds[r * 64 + p * 8]);
            }
            for (int j = 0; j < 4; ++j) {
                int nr = wn + j * 16 + m_lane;
                int p = cbase ^ (nr & 7);
                bfr[j] = *(const bf16x8*)(&slds[8192 + nr * 64 + p * 8]);
            }
            for (int i = 0; i < 4; ++i)
                for (int j = 0; j < 4; ++j)
                    acc[i][j] = __builtin_amdgcn_mfma_f32_16x16x32_bf16(
                        af[i], bfr[j], acc[i][j], 0, 0, 0);
        }
        __syncthreads();
    }

    for (int j = 0; j < 4; ++j) {
        int col = n0 + wn + j * 16 + m_lane;
        float bj = bias[col];
        for (int i = 0; i < 4; ++i) {
            int rbase = m0 + wm + i * 16 + kq * 4;
            for (int rg = 0; rg < 4; ++rg)
                out[(size_t)(rbase + rg) * HIDDEN + col] = acc[i][j][rg] + bj;
        }
    }
}

// ---------------------------------------------------------------------------
extern "C" void kernel_launch(void* const* d_in, const int* in_sizes, int n_in,
                              void* d_out, int out_size, void* d_ws, size_t ws_size,
                              hipStream_t stream) {
    const float* Xq = (const float*)d_in[0];
    const float* Xk = (const float*)d_in[1];
    const float* Xv = (const float*)d_in[2];
    const float* Wq = (const float*)d_in[3];
    const float* Bq = (const float*)d_in[4];
    const float* Wk = (const float*)d_in[5];
    const float* Bk = (const float*)d_in[6];
    const float* Wv = (const float*)d_in[7];
    const float* Bv = (const float*)d_in[8];
    float* out = (float*)d_out;

    char* ws = (char*)d_ws;
    uint16_t* Xb = (uint16_t*)ws;                        // 50,331,648 B (Xq,Xk,Xv bf16)
    uint16_t* KV = (uint16_t*)(ws + 50331648);           // 33,554,432 B (K,V bf16)
    uint16_t* Wt = (uint16_t*)(ws + 83886080);           //  4,194,304 B (Wk,Wv bf16 T)
    float* P = (float*)(ws + 88080384);                  //  8,388,608 B (64bh x 8sc x 4096)
    uint16_t* Wpt = (uint16_t*)(ws + 96468992);          //  8,388,608 B (4 x W'_b)
    float* bp = (float*)(ws + 104857600);                //     16,384 B (~100 MB)

    cvt_kernel<<<dim3(3 * 8192), 256, 0, stream>>>(Xq, Xk, Xv, Xb);
    wt_kernel<<<dim3(16, 16, 2), 256, 0, stream>>>(Wk, Wv, Wt);

    const uint16_t* Xkv = Xb + (size_t)ROWS * HIDDEN;
    proj_gemm<<<dim3(64, 8, 2), 256, 0, stream>>>(Xkv, Wt, Bk, Bv, KV);
    kv_kernel<<<dim3(64, 8), 256, 0, stream>>>(KV, P);
    wprime_kernel<<<dim3(16, 16, 4), 256, 0, stream>>>(Wq, Bq, P, Wpt, bp);
    final_gemm<<<dim3(64, 8), 256, 0, stream>>>(Xb, Wpt, bp, out);
}